// Round 3
// baseline (768.360 us; speedup 1.0000x reference)
//
#include <hip/hip_runtime.h>
#include <hip/hip_bf16.h>
#include <stdint.h>

#define DM 1024            // d_model
#define DN 4096            // d_neuron
#define BB 2               // batch
#define TT 4096            // seq
#define MR (BB*TT)         // 8192 total GEMM rows
#define TC 512             // time chunk
#define NTC (TT/TC)        // 8 time chunks
#define CR (BB*TC)         // 1024 rows per chunk
#define CN ((size_t)CR*DN) // per-chunk activation elems (4,194,304)
#define SCH 16             // scan sub-chunk (32 tg x 16 = TC)

typedef unsigned short u16;
typedef __attribute__((ext_vector_type(8))) short bf16x8;
typedef __attribute__((ext_vector_type(4))) float f32x4;

__device__ __forceinline__ float bf2f(u16 u) {
    unsigned int x = ((unsigned int)u) << 16; float f; __builtin_memcpy(&f, &x, 4); return f;
}
__device__ __forceinline__ u16 f2bf(float f) {
    __hip_bfloat16 h = __float2bfloat16(f); u16 u; __builtin_memcpy(&u, &h, 2); return u;
}
// fast tanh: 1 - 2/(exp(2x)+1); exact at +-inf, abs err ~1e-7
__device__ __forceinline__ float tanh_fast(float x) {
    float e = __expf(2.f * x);
    return 1.f - 2.f / (e + 1.f);
}
// A&S 7.1.26 erf poly, max abs err 1.5e-7
__device__ __forceinline__ float erf_fast(float x) {
    float ax = fabsf(x);
    float t = 1.f / (1.f + 0.3275911f * ax);
    float y = t * (0.254829592f + t * (-0.284496736f + t * (1.421413741f +
              t * (-1.453152027f + t * 1.061405429f))));
    float r = 1.f - y * __expf(-ax * ax);
    return copysignf(r, x);
}
// async global->LDS, 16 B per lane (dest = wave-uniform base + lane*16)
__device__ __forceinline__ void async16(const void* g, void* l) {
    __builtin_amdgcn_global_load_lds(
        (const __attribute__((address_space(1))) void*)(uintptr_t)g,
        (__attribute__((address_space(3))) void*)(uint32_t)(uintptr_t)l,
        16, 0, 0);
}

// -------- fused conversion: x + 4 proj weights + W_out (fp32->bf16) + state copy --------
__global__ void cvt7_kernel(const float4* __restrict__ x,
                            const float4* __restrict__ w0, const float4* __restrict__ w1,
                            const float4* __restrict__ w2, const float4* __restrict__ w3,
                            const float4* __restrict__ wo, const float4* __restrict__ st,
                            ushort4* __restrict__ xb, ushort4* __restrict__ w4b,
                            ushort4* __restrict__ woutb, float4* __restrict__ state_cur)
{
    const int XQ = (MR * DM) / 4;        // 2,097,152
    const int WQ = (DN * DM) / 4;        // 1,048,576 = 2^20
    const int SQ = XQ + 5 * WQ;          // start of state segment
    int i = blockIdx.x * 256 + threadIdx.x;
    if (i >= SQ) {                        // state passthrough (BB*DN/4 = 2048 float4)
        int j = i - SQ;
        if (j < (BB * DN) / 4) state_cur[j] = st[j];
        return;
    }
    const float4* s; ushort4* d;
    if (i < XQ) { s = x + i; d = xb + i; }
    else {
        int j = i - XQ;
        int seg = j >> 20;
        int off = j & (WQ - 1);
        if (seg < 4) {
            const float4* ws = (seg == 0) ? w0 : (seg == 1) ? w1 : (seg == 2) ? w2 : w3;
            s = ws + off; d = w4b + j;
        } else {
            s = wo + off; d = woutb + off;
        }
    }
    float4 v = *s;
    ushort4 o; o.x = f2bf(v.x); o.y = f2bf(v.y); o.z = f2bf(v.z); o.w = f2bf(v.w);
    *d = o;
}

#define BM 128
#define BN 128
#define BK 64

// ================= ROUND-10: 256^2 8-phase gemm4, unrolled + MFMA-spaced =================
// Round-9 result: correct but 74.6us (460 TF) vs m248 reference ~848 TF at this
// structure+shape. Two suspects fixed this round (numerics + sync schedule UNCHANGED):
//  (a) dependent back-to-back MFMA pairs into the same acc (k-half inner) -> latency-
//      bound MFMA cluster if the scheduler doesn't interleave. Now k-half is the OUTER
//      loop: each acc's two updates are 8 MFMAs apart (per-acc order unchanged ->
//      bit-identical results).
//  (b) runtime (t&1) buffer selects + in-loop guards -> 2-K-tile unroll with literal
//      LDS bases (As0/Bs0/As1/Bs1) and peeled tiles 14/15; staging schedule verbatim:
//   tile t: p0: S(t+1,A-h1)->other  p1: S(t+2,B-h0)->cur  p2: S(t+2,B-h1)->cur
//           p3: S(t+2,A-h0)->cur, then vmcnt(6)   [t=14: only p0 stage, vmcnt(0)]
//   B region dead after p0 (register-hoisted); A-h0 dead after p1; A-h1 after p3.

#define G4_BM 256
#define G4_BN 256
#define G4_BK 64
#define G4_NT (DM/G4_BK)        // 16 K-tiles
#define G4_TSZ (G4_BM*G4_BK)    // 16384 u16 = 32 KB per tile buffer; 4 buffers = 128 KB

__device__ __forceinline__ void stage_half_B(const u16* __restrict__ Wp, u16* lds_tile,
                                             int n0, int r0, int kt, int tid)
{
    const int lane = tid & 63;
    const int wv = tid >> 6;
#pragma unroll
    for (int l = 0; l < 2; ++l) {
        const int r = r0 + (wv * 2 + l) * 8 + (lane >> 3);   // tile row 0..255
        const int cg = (lane & 7) ^ (r & 7);                 // pre-swizzled global chunk
        async16(Wp + (size_t)(n0 + r) * DM + kt + cg * 8,
                lds_tile + (size_t)(r0 + (wv * 2 + l) * 8) * G4_BK);
    }
}

__device__ __forceinline__ void stage_half_A(const u16* __restrict__ Xb, u16* lds_tile,
                                             int m0, int r0, int kt, int ci, int tid)
{
    const int lane = tid & 63;
    const int wv = tid >> 6;
#pragma unroll
    for (int l = 0; l < 2; ++l) {
        const int r = r0 + (wv * 2 + l) * 8 + (lane >> 3);
        const int cg = (lane & 7) ^ (r & 7);
        const int lr = m0 + r;                               // chunk-local row 0..1023
        const int xrow = ((lr >> 9) << 12) + ci * TC + (lr & (TC - 1));
        async16(Xb + (size_t)xrow * DM + kt + cg * 8,
                lds_tile + (size_t)(r0 + (wv * 2 + l) * 8) * G4_BK);
    }
}

// one phase: 8x ds_read_b128 (A quarter Q from literal base ASC) || stage || [vmcnt]
// || barrier || lgkmcnt(0)+sched_barrier (rule 18) || setprio(1) 16x MFMA (k-half
// OUTER: dependent acc updates 8 apart) setprio(0) || barrier
#define PH(Q, ASC, STAGE_STMT, VMCNT_STMT)                                         \
  {                                                                                \
    bf16x8 af[4][2];                                                               \
    _Pragma("unroll")                                                              \
    for (int i_ = 0; i_ < 4; ++i_) {                                               \
      const int row_ = (Q) * 64 + i_ * 16 + l16;                                   \
      const int rx_ = row_ & 7;                                                    \
      af[i_][0] = *(const bf16x8*)(ASC + row_ * G4_BK + ((quad ^ rx_) * 8));       \
      af[i_][1] = *(const bf16x8*)(ASC + row_ * G4_BK + (((4 + quad) ^ rx_) * 8)); \
    }                                                                              \
    STAGE_STMT                                                                     \
    VMCNT_STMT                                                                     \
    __builtin_amdgcn_s_barrier();                                                  \
    asm volatile("s_waitcnt lgkmcnt(0)" ::: "memory");                             \
    __builtin_amdgcn_sched_barrier(0);                                             \
    __builtin_amdgcn_s_setprio(1);                                                 \
    _Pragma("unroll")                                                              \
    for (int h_ = 0; h_ < 2; ++h_)                                                 \
      _Pragma("unroll")                                                            \
      for (int i_ = 0; i_ < 4; ++i_)                                               \
        _Pragma("unroll")                                                          \
        for (int j_ = 0; j_ < 2; ++j_)                                             \
          acc[(Q) * 4 + i_][j_] = __builtin_amdgcn_mfma_f32_16x16x32_bf16(         \
              af[i_][h_], bf[j_][h_], acc[(Q) * 4 + i_][j_], 0, 0, 0);             \
    __builtin_amdgcn_s_setprio(0);                                                 \
    __builtin_amdgcn_sched_barrier(0);                                             \
    __builtin_amdgcn_s_barrier();                                                  \
  }

// B-frags for the whole K-tile, register-hoisted (B region dead after phase 0)
#define BFLOAD(BSC)                                                                \
    bf16x8 bf[2][2];                                                               \
    _Pragma("unroll")                                                              \
    for (int j_ = 0; j_ < 2; ++j_) {                                               \
      const int row_ = wv * 32 + j_ * 16 + l16;                                    \
      const int rx_ = row_ & 7;                                                    \
      bf[j_][0] = *(const bf16x8*)(BSC + row_ * G4_BK + ((quad ^ rx_) * 8));       \
      bf[j_][1] = *(const bf16x8*)(BSC + row_ * G4_BK + (((4 + quad) ^ rx_) * 8)); \
    }

#define TILE_FULL(ASC, BSC, ASN, T)                                                \
  {                                                                                \
    BFLOAD(BSC)                                                                    \
    PH(0, ASC, stage_half_A(Xb, ASN, m0, 128, ((T) + 1) * G4_BK, ci, tid);, )      \
    PH(1, ASC, stage_half_B(Wp, BSC, n0, 0, ((T) + 2) * G4_BK, tid);, )            \
    PH(2, ASC, stage_half_B(Wp, BSC, n0, 128, ((T) + 2) * G4_BK, tid);, )          \
    PH(3, ASC, stage_half_A(Xb, ASC, m0, 0, ((T) + 2) * G4_BK, ci, tid);,          \
       asm volatile("s_waitcnt vmcnt(6)" ::: "memory");)                           \
  }

__global__ __launch_bounds__(512, 2) void gemm4_8ph(
    const u16* __restrict__ Xb,             // bf16 [8192][1024]
    const u16* __restrict__ W4b,            // bf16 [4][4096][1024]
    u16* __restrict__ raw_o, u16* __restrict__ sig_o,
    u16* __restrict__ modp_o, u16* __restrict__ omd_o,
    const float* __restrict__ A_log, const float* __restrict__ b_delta, int ci)
{
    extern __shared__ u16 lds[];            // 131072 B dynamic
    u16* const As0 = lds;
    u16* const Bs0 = lds + G4_TSZ;
    u16* const As1 = lds + 2 * G4_TSZ;
    u16* const Bs1 = lds + 3 * G4_TSZ;

    const int bid = blockIdx.x;             // 0..255 (1 block/CU)
    const int xcd = bid & 7;
    const int g = bid >> 3;                 // 0..31
    const int m_idx = g & 3;                // 4 m-tiles
    const int pair = xcd * 8 + (g >> 2);    // 0..63 = 16 n-tiles x 4 w; 8 pairs/XCD
    const int n_idx = pair & 15;            //   -> per-XCD W set = 8*256*1024*2B = 4MB = L2
    const int w = pair >> 4;

    const u16* __restrict__ Wp = W4b + (size_t)w * DN * DM;
    u16* __restrict__ Op = (w == 0) ? raw_o : (w == 1) ? sig_o : (w == 2) ? modp_o : omd_o;
    const int n0 = n_idx * G4_BN;
    const int m0 = m_idx * G4_BM;

    const int tid = threadIdx.x;
    const int lane = tid & 63;
    const int wv = tid >> 6;                // 0..7, 1M x 8N: wave owns 256 x 32 output
    const int l16 = lane & 15;
    const int quad = lane >> 4;

    const f32x4 z4 = {0.f, 0.f, 0.f, 0.f};
    f32x4 acc[16][2];                       // 128 VGPR accumulator (by design, 1 blk/CU)
#pragma unroll
    for (int i = 0; i < 16; ++i) { acc[i][0] = z4; acc[i][1] = z4; }

    // prologue: 7 half-tiles (tile 0 complete + 3 halves of tile 1 in flight)
    stage_half_B(Wp, Bs0, n0, 0,   0, tid);
    stage_half_B(Wp, Bs0, n0, 128, 0, tid);
    stage_half_A(Xb, As0, m0, 0,   0, ci, tid);
    stage_half_A(Xb, As0, m0, 128, 0, ci, tid);
    stage_half_B(Wp, Bs1, n0, 0,   G4_BK, tid);
    stage_half_B(Wp, Bs1, n0, 128, G4_BK, tid);
    stage_half_A(Xb, As1, m0, 0,   G4_BK, ci, tid);
    asm volatile("s_waitcnt vmcnt(6)" ::: "memory");
    __builtin_amdgcn_s_barrier();

    // tiles 0..13: 7 unrolled even/odd pairs, full staging, vmcnt(6)
    for (int tp = 0; tp < 7; ++tp) {
        const int t0 = tp * 2;
        TILE_FULL(As0, Bs0, As1, t0)
        TILE_FULL(As1, Bs1, As0, t0 + 1)
    }
    // tile 14 (even: As0/Bs0): only p0 stage A(15)h1 -> As1; drain vmcnt(0) at p3
    {
        BFLOAD(Bs0)
        PH(0, As0, stage_half_A(Xb, As1, m0, 128, 15 * G4_BK, ci, tid);, )
        PH(1, As0, , )
        PH(2, As0, , )
        PH(3, As0, , asm volatile("s_waitcnt vmcnt(0)" ::: "memory");)
    }
    // tile 15 (odd: As1/Bs1): no staging, nothing outstanding
    {
        BFLOAD(Bs1)
        PH(0, As1, , )
        PH(1, As1, , )
        PH(2, As1, , )
        PH(3, As1, , )
    }

    // hoisted per-column params for w=3 (n depends only on j)
    float Aj[2], bdj[2];
    if (w == 3) {
#pragma unroll
        for (int j = 0; j < 2; ++j) {
            int n = n0 + wv * 32 + j * 16 + l16;
            Aj[j] = __expf(A_log[n]);
            bdj[j] = b_delta[n];
        }
    }

    // epilogue: C/D layout col=lane&15, row=quad*4+reg (m89-verified); 16 M-frags
#pragma unroll
    for (int f = 0; f < 16; ++f) {
#pragma unroll
        for (int j = 0; j < 2; ++j) {
            const int n = n0 + wv * 32 + j * 16 + l16;
#pragma unroll
            for (int r = 0; r < 4; ++r) {
                const int m = m0 + f * 16 + quad * 4 + r;
                float z = acc[f][j][r];
                float o;
                if (w == 0) {
                    o = z;                                    // raw
                } else if (w == 1) {
                    o = 1.f / (1.f + __expf(-z));             // sigmoid gate
                } else if (w == 2) {
                    o = 1.f + tanh_fast(z);                   // 1 + mod
                } else {
                    float v = z + bdj[j];                     // softplus, stable
                    float sp = fmaxf(v, 0.f) + __logf(1.f + __expf(-fabsf(v)));
                    o = 1.f - __expf(-Aj[j] * sp);            // 1 - decay
                }
                Op[(size_t)m * DN + n] = f2bf(o);
            }
        }
    }
}

// ---------------- output GEMM: out[m][dm] = sum_k Z[m][k]*W_out[dm][k], K=4096 ----------------
// ROUND-6 VERBATIM (at ~900 TF m97-structure plateau, FETCH ideal).
__global__ __launch_bounds__(256, 4) void gemm_out_kernel(
    const u16* __restrict__ Zb, const u16* __restrict__ Wob, float* __restrict__ Out)
{
    const int bid = blockIdx.x;              // 0..511
    const int xcd = bid & 7;
    const int g = bid >> 3;                  // 0..63
    const int n_idx = g & 7;
    const int m_idx = xcd * 8 + (g >> 3);    // 0..63
    const int n0 = n_idx * BN;
    const int m0 = m_idx * BM;

    alignas(16) __shared__ u16 As[BM * BK];
    alignas(16) __shared__ u16 Bs[BN * BK];

    const int tid = threadIdx.x;
    const int lane = tid & 63;
    const int wave = tid >> 6;
    const int wm = (wave >> 1) * 64;
    const int wn = (wave & 1) * 64;
    const int l16 = lane & 15;
    const int quad = lane >> 4;
    const int sr8 = lane >> 3;
    const int cl = lane & 7;

    const f32x4 z4 = {0.f, 0.f, 0.f, 0.f};
    f32x4 acc[4][4];
#pragma unroll
    for (int i = 0; i < 4; i++)
#pragma unroll
        for (int j = 0; j < 4; j++) acc[i][j] = z4;

    for (int kt = 0; kt < DN; kt += BK) {
        __syncthreads();
#pragma unroll
        for (int it = 0; it < 4; ++it) {
            const int r = wave * 32 + it * 8 + sr8;
            const int cg = cl ^ (r & 7);
            async16(Zb + (size_t)(m0 + r) * DN + kt + cg * 8,
                    As + (wave * 32 + it * 8) * BK);
            async16(Wob + (size_t)(n0 + r) * DN + kt + cg * 8,
                    Bs + (wave * 32 + it * 8) * BK);
        }
        __syncthreads();
#pragma unroll
        for (int ks = 0; ks < BK; ks += 32) {
            bf16x8 af[4], bfr[4];
#pragma unroll
            for (int i = 0; i < 4; i++) {
                const int r = wm + i * 16 + l16;
                const int ch = ((ks >> 3) + quad) ^ (r & 7);
                af[i] = *(const bf16x8*)(As + r * BK + ch * 8);
            }
#pragma unroll
            for (int j = 0; j < 4; j++) {
                const int r = wn + j * 16 + l16;
                const int ch = ((ks >> 3) + quad) ^ (r & 7);
                bfr[j] = *(const bf16x8*)(Bs + r * BK + ch * 8);
            }
#pragma unroll
            for (int i = 0; i < 4; i++)
#pragma unroll
                for (int j = 0; j < 4; j++)
                    acc[i][j] = __builtin_amdgcn_mfma_f32_16x16x32_bf16(af[i], bfr[j], acc[i][j], 0, 0, 0);
        }
    }

#pragma unroll
    for (int i = 0; i < 4; i++)
#pragma unroll
        for (int j = 0; j < 4; j++) {
            int n = n0 + wn + j * 16 + l16;
#pragma unroll
            for (int r = 0; r < 4; r++) {
                int m = m0 + wm + i * 16 + quad * 4 + r;
                Out[(size_t)m * DM + n] = acc[i][j][r];
            }
        }
}

// ---------------- single-pass hierarchical scan for one time chunk ----------------
// Block = (batch b, 32-neuron slice), 1024 threads = 32 tg x 32 neurons. Phase 1 computes
// AND REGISTER-HOLDS per-step d, u, y=mp*(1-sw)*gelu(raw), msw=mp*sw (64 VGPRs, unrolled);
// phase 2 is pure register math + Z stores -> activations read ONCE (42 vs 67 MB/chunk).
__global__ __launch_bounds__(1024) void scan_fused(
    const u16* __restrict__ omd_a, const u16* __restrict__ sig_a,
    const u16* __restrict__ raw_a, const u16* __restrict__ modp_a,
    float* __restrict__ state_cur, const float* __restrict__ sw_logit,
    u16* __restrict__ Z, float* __restrict__ fs_out, int ci_t)
{
    __shared__ float Ds[32][32];
    __shared__ float Ss[32][32];
    __shared__ float Is[32][32];

    const int tid = threadIdx.x;
    const int nl = tid & 31;
    const int tg = tid >> 5;
    const int bx = blockIdx.x;               // BB * (DN/32) = 256 blocks
    const int nsl = bx & 127;
    const int b = bx >> 7;
    const int n = nsl * 32 + nl;

    const size_t base = ((size_t)(b * TC + tg * SCH)) * DN + n;   // chunk-local rows

    const float sw = 1.f / (1.f + __expf(-sw_logit[n]));
    const float osw = 1.f - sw;

    float dv[SCH], uv[SCH], yv[SCH], mswv[SCH];

    // phase 1: sub-chunk summary, hold recurrence inputs in registers
    float D = 1.f, s = 0.f;
#pragma unroll
    for (int t = 0; t < SCH; t++) {
        size_t idx = base + (size_t)t * DN;
        float omd = bf2f(omd_a[idx]);
        float sg = bf2f(sig_a[idx]);
        float rw = bf2f(raw_a[idx]);
        float mp = bf2f(modp_a[idx]);
        float d = 1.f - omd;
        float u = omd * sg * tanh_fast(rw);
        float g2 = 0.5f * rw * (1.f + erf_fast(rw * 0.70710678f));  // exact gelu
        dv[t] = d; uv[t] = u;
        yv[t] = mp * osw * g2;
        mswv[t] = mp * sw;
        D *= d;
        s = d * s + u;
    }
    Ds[tg][nl] = D;
    Ss[tg][nl] = s;
    __syncthreads();

    // prefix combine: tg==0 threads (one per neuron) walk the 32 summaries
    if (tg == 0) {
        float si = state_cur[b * DN + n];
        Is[0][nl] = si;
        for (int c = 0; c < 31; c++) {
            si = Ds[c][nl] * si + Ss[c][nl];
            Is[c + 1][nl] = si;
        }
    }
    __syncthreads();

    // phase 2: register-only re-scan, emit Z
    float s2 = Is[tg][nl];
    const size_t gbase = ((size_t)(b * TT + ci_t * TC + tg * SCH)) * DN + n;
#pragma unroll
    for (int t = 0; t < SCH; t++) {
        s2 = dv[t] * s2 + uv[t];
        Z[gbase + (size_t)t * DN] = f2bf(yv[t] + mswv[t] * s2);
    }
    if (tg == 31) {
        state_cur[b * DN + n] = s2;                 // carry to next chunk
        if (ci_t == NTC - 1) fs_out[b * DN + n] = s2;  // final_state output
    }
}

// ---------------- host launcher ----------------
extern "C" void kernel_launch(void* const* d_in, const int* in_sizes, int n_in,
                              void* d_out, int out_size, void* d_ws, size_t ws_size,
                              hipStream_t stream)
{
    const float* x = (const float*)d_in[0];
    const float* state = (const float*)d_in[1];
    const float* W_main = (const float*)d_in[2];
    const float* W_gate = (const float*)d_in[3];
    const float* W_mod = (const float*)d_in[4];
    const float* W_out = (const float*)d_in[5];
    const float* W_delta = (const float*)d_in[6];
    const float* b_delta = (const float*)d_in[7];
    const float* A_log = (const float*)d_in[8];
    const float* sw_logit = (const float*)d_in[9];

    float* out = (float*)d_out;                       // [B,T,Dm] fp32
    float* fs_out = out + (size_t)MR * DM;            // final_state [B,Dn]

    const size_t NM = (size_t)MR * DN;
    u16* Zb = (u16*)d_ws;                             // 67.11 MB
    u16* raw_c = Zb + NM;                             // 4 x 8.39 MB
    u16* sig_c = raw_c + CN;
    u16* modp_c = sig_c + CN;
    u16* omd_c = modp_c + CN;
    u16* W4b = omd_c + CN;                            // 33.55 MB
    u16* xb = W4b + (size_t)4 * DN * DM;              // 16.78 MB
    u16* woutb = xb + (size_t)MR * DM;                // 8.39 MB
    float* state_cur = (float*)(woutb + (size_t)DM * DN); // 32 KB
    // total = 159,416,320 B  (< 160,202,752 proven available)

    // allow 128 KiB dynamic LDS for the 8-phase GEMM (once per process)
    static bool attr_set = false;
    if (!attr_set) {
        (void)hipFuncSetAttribute((const void*)gemm4_8ph,
                                  hipFuncAttributeMaxDynamicSharedMemorySize,
                                  4 * G4_TSZ * (int)sizeof(u16));
        attr_set = true;
    }

    // one fused conversion launch: x + 4 proj weights + W_out + state copy
    {
        const int total4 = (MR * DM) / 4 + 5 * ((DN * DM) / 4) + (BB * DN) / 4;
        cvt7_kernel<<<(total4 + 255) / 256, 256, 0, stream>>>(
            (const float4*)x, (const float4*)W_main, (const float4*)W_gate,
            (const float4*)W_mod, (const float4*)W_delta, (const float4*)W_out,
            (const float4*)state,
            (ushort4*)xb, (ushort4*)W4b, (ushort4*)woutb, (float4*)state_cur);
    }

    for (int ci = 0; ci < NTC; ci++) {
        gemm4_8ph<<<256, 512, 4 * G4_TSZ * sizeof(u16), stream>>>(
            xb, W4b, raw_c, sig_c, modp_c, omd_c, A_log, b_delta, ci);
        scan_fused<<<BB * (DN / 32), 1024, 0, stream>>>(omd_c, sig_c, raw_c, modp_c,
                                                        state_cur, sw_logit,
                                                        Zb, fs_out, ci);
    }

    gemm_out_kernel<<<512, 256, 0, stream>>>(Zb, woutb, out);
}

// Round 4
// 752.598 us; speedup vs baseline: 1.0209x; 1.0209x over previous
//
#include <hip/hip_runtime.h>
#include <hip/hip_bf16.h>
#include <stdint.h>

#define DM 1024            // d_model
#define DN 4096            // d_neuron
#define BB 2               // batch
#define TT 4096            // seq
#define MR (BB*TT)         // 8192 total GEMM rows
#define TC 512             // time chunk
#define NTC (TT/TC)        // 8 time chunks
#define CR (BB*TC)         // 1024 rows per chunk
#define CN ((size_t)CR*DN) // per-chunk activation elems (4,194,304)
#define SCH 16             // scan sub-chunk (32 tg x 16 = TC)

typedef unsigned short u16;
typedef __attribute__((ext_vector_type(8))) short bf16x8;
typedef __attribute__((ext_vector_type(4))) float f32x4;

__device__ __forceinline__ float bf2f(u16 u) {
    unsigned int x = ((unsigned int)u) << 16; float f; __builtin_memcpy(&f, &x, 4); return f;
}
__device__ __forceinline__ u16 f2bf(float f) {
    __hip_bfloat16 h = __float2bfloat16(f); u16 u; __builtin_memcpy(&u, &h, 2); return u;
}
// fast tanh: 1 - 2/(exp(2x)+1); exact at +-inf, abs err ~1e-7
__device__ __forceinline__ float tanh_fast(float x) {
    float e = __expf(2.f * x);
    return 1.f - 2.f / (e + 1.f);
}
// A&S 7.1.26 erf poly, max abs err 1.5e-7
__device__ __forceinline__ float erf_fast(float x) {
    float ax = fabsf(x);
    float t = 1.f / (1.f + 0.3275911f * ax);
    float y = t * (0.254829592f + t * (-0.284496736f + t * (1.421413741f +
              t * (-1.453152027f + t * 1.061405429f))));
    float r = 1.f - y * __expf(-ax * ax);
    return copysignf(r, x);
}
// async global->LDS, 16 B per lane (dest = wave-uniform base + lane*16)
__device__ __forceinline__ void async16(const void* g, void* l) {
    __builtin_amdgcn_global_load_lds(
        (const __attribute__((address_space(1))) void*)(uintptr_t)g,
        (__attribute__((address_space(3))) void*)(uint32_t)(uintptr_t)l,
        16, 0, 0);
}

// -------- fused conversion: x + 4 proj weights + W_out (fp32->bf16) + state copy --------
__global__ void cvt7_kernel(const float4* __restrict__ x,
                            const float4* __restrict__ w0, const float4* __restrict__ w1,
                            const float4* __restrict__ w2, const float4* __restrict__ w3,
                            const float4* __restrict__ wo, const float4* __restrict__ st,
                            ushort4* __restrict__ xb, ushort4* __restrict__ w4b,
                            ushort4* __restrict__ woutb, float4* __restrict__ state_cur)
{
    const int XQ = (MR * DM) / 4;        // 2,097,152
    const int WQ = (DN * DM) / 4;        // 1,048,576 = 2^20
    const int SQ = XQ + 5 * WQ;          // start of state segment
    int i = blockIdx.x * 256 + threadIdx.x;
    if (i >= SQ) {                        // state passthrough (BB*DN/4 = 2048 float4)
        int j = i - SQ;
        if (j < (BB * DN) / 4) state_cur[j] = st[j];
        return;
    }
    const float4* s; ushort4* d;
    if (i < XQ) { s = x + i; d = xb + i; }
    else {
        int j = i - XQ;
        int seg = j >> 20;
        int off = j & (WQ - 1);
        if (seg < 4) {
            const float4* ws = (seg == 0) ? w0 : (seg == 1) ? w1 : (seg == 2) ? w2 : w3;
            s = ws + off; d = w4b + j;
        } else {
            s = wo + off; d = woutb + off;
        }
    }
    float4 v = *s;
    ushort4 o; o.x = f2bf(v.x); o.y = f2bf(v.y); o.z = f2bf(v.z); o.w = f2bf(v.w);
    *d = o;
}

#define BM 128
#define BN 128
#define BK 64

// ---------------- 4 input projections for one time chunk, fused activations ----------------
// ROUND-11: REVERTED to the round-0/round-6 VERBATIM 128^2 kernel (best-known: 723 us
// total, gemm4 ~70 us/launch ~ 460 TF). 8-phase 256^2 experiments (rounds 8-10) were
// NEUTRAL-to-worse (75 us) -> both structures cap at ~460 TF on THIS shape, so the
// bottleneck is NOT the K-loop schedule. This round surfaces gemm4's counters (see
// gemm_out split below) to find the real limiter before the next edit.
// XCD x owns (n,w) pairs [x*16,x*16+16); 8 m-blocks per pair co-resident -> per-XCD W
// working set 4MB = L2. Keep acc <= 64 AGPRs and >= 4 blocks/CU (round-7 lesson).
__global__ __launch_bounds__(256, 4) void gemm4_kernel(
    const u16* __restrict__ Xb,             // bf16 [8192][1024]
    const u16* __restrict__ W4b,            // bf16 [4][4096][1024]
    u16* __restrict__ raw_o, u16* __restrict__ sig_o,
    u16* __restrict__ modp_o, u16* __restrict__ omd_o,
    const float* __restrict__ A_log, const float* __restrict__ b_delta, int ci)
{
    const int bid = blockIdx.x;              // 0..1023
    const int xcd = bid & 7;
    const int g = bid >> 3;                  // 0..127
    const int m_idx = g & 7;
    const int pair = xcd * 16 + (g >> 3);    // 0..127 = 32 n-tiles x 4 w
    const int n_idx = pair & 31;
    const int w = pair >> 5;

    const u16* Wp = W4b + (size_t)w * DN * DM;
    u16* Op = (w == 0) ? raw_o : (w == 1) ? sig_o : (w == 2) ? modp_o : omd_o;
    const int n0 = n_idx * BN;
    const int m0 = m_idx * BM;

    alignas(16) __shared__ u16 As[BM * BK];
    alignas(16) __shared__ u16 Bs[BN * BK];

    const int tid = threadIdx.x;
    const int lane = tid & 63;
    const int wave = tid >> 6;
    const int wm = (wave >> 1) * 64;
    const int wn = (wave & 1) * 64;
    const int l16 = lane & 15;
    const int quad = lane >> 4;
    const int sr8 = lane >> 3;
    const int cl = lane & 7;

    const f32x4 z4 = {0.f, 0.f, 0.f, 0.f};
    f32x4 acc[4][4];
#pragma unroll
    for (int i = 0; i < 4; i++)
#pragma unroll
        for (int j = 0; j < 4; j++) acc[i][j] = z4;

    for (int kt = 0; kt < DM; kt += BK) {
        __syncthreads();
#pragma unroll
        for (int it = 0; it < 4; ++it) {
            const int r = wave * 32 + it * 8 + sr8;
            const int cg = cl ^ (r & 7);                  // XOR-8 swizzle
            async16(Wp + (size_t)(n0 + r) * DM + kt + cg * 8,
                    Bs + (wave * 32 + it * 8) * BK);
            const int lr = m0 + r;
            const int xrow = ((lr >> 9) << 12) + ci * TC + (lr & (TC - 1));
            async16(Xb + (size_t)xrow * DM + kt + cg * 8,
                    As + (wave * 32 + it * 8) * BK);
        }
        __syncthreads();
#pragma unroll
        for (int ks = 0; ks < BK; ks += 32) {
            bf16x8 af[4], bfr[4];
#pragma unroll
            for (int i = 0; i < 4; i++) {
                const int r = wm + i * 16 + l16;
                const int ch = ((ks >> 3) + quad) ^ (r & 7);
                af[i] = *(const bf16x8*)(As + r * BK + ch * 8);
            }
#pragma unroll
            for (int j = 0; j < 4; j++) {
                const int r = wn + j * 16 + l16;
                const int ch = ((ks >> 3) + quad) ^ (r & 7);
                bfr[j] = *(const bf16x8*)(Bs + r * BK + ch * 8);
            }
#pragma unroll
            for (int i = 0; i < 4; i++)
#pragma unroll
                for (int j = 0; j < 4; j++)
                    acc[i][j] = __builtin_amdgcn_mfma_f32_16x16x32_bf16(af[i], bfr[j], acc[i][j], 0, 0, 0);
        }
    }

    // hoisted per-column params for w=3 (n depends only on j)
    float Aj[4], bdj[4];
    if (w == 3) {
#pragma unroll
        for (int j = 0; j < 4; j++) {
            int n = n0 + wn + j * 16 + l16;
            Aj[j] = __expf(A_log[n]);
            bdj[j] = b_delta[n];
        }
    }

    // epilogue: C/D layout col=lane&15, row=quad*4+reg (m89-verified)
#pragma unroll
    for (int i = 0; i < 4; i++) {
#pragma unroll
        for (int j = 0; j < 4; j++) {
            int n = n0 + wn + j * 16 + l16;
#pragma unroll
            for (int r = 0; r < 4; r++) {
                int m = m0 + wm + i * 16 + quad * 4 + r;
                float z = acc[i][j][r];
                float o;
                if (w == 0) {
                    o = z;                                    // raw
                } else if (w == 1) {
                    o = 1.f / (1.f + __expf(-z));             // sigmoid gate
                } else if (w == 2) {
                    o = 1.f + tanh_fast(z);                   // 1 + mod
                } else {
                    float v = z + bdj[j];                     // softplus, stable
                    float sp = fmaxf(v, 0.f) + __logf(1.f + __expf(-fabsf(v)));
                    o = 1.f - __expf(-Aj[j] * sp);            // 1 - decay
                }
                Op[(size_t)m * DN + n] = f2bf(o);
            }
        }
    }
}

// ---------------- output GEMM: out[m][dm] = sum_k Z[m][k]*W_out[dm][k], K=4096 ----------------
// ROUND-11: body VERBATIM round-6; split into TWO half-M launches (m_base = 0, 32) so
// each half (~39-44 us) drops below gemm4 (~70 us) and the top-5 profiler window finally
// shows gemm4's counters. Decomposition per launch: 256 blocks, m_idx = m_base + xcd*4
// + (g>>3), n_idx = g&7 (bijective over 32 m-tiles x 8 n-tiles).
__global__ __launch_bounds__(256, 4) void gemm_out_kernel(
    const u16* __restrict__ Zb, const u16* __restrict__ Wob, float* __restrict__ Out,
    int m_base)
{
    const int bid = blockIdx.x;              // 0..255
    const int xcd = bid & 7;
    const int g = bid >> 3;                  // 0..31
    const int n_idx = g & 7;
    const int m_idx = m_base + xcd * 4 + (g >> 3);   // 32 m-tiles per launch
    const int n0 = n_idx * BN;
    const int m0 = m_idx * BM;

    alignas(16) __shared__ u16 As[BM * BK];
    alignas(16) __shared__ u16 Bs[BN * BK];

    const int tid = threadIdx.x;
    const int lane = tid & 63;
    const int wave = tid >> 6;
    const int wm = (wave >> 1) * 64;
    const int wn = (wave & 1) * 64;
    const int l16 = lane & 15;
    const int quad = lane >> 4;
    const int sr8 = lane >> 3;
    const int cl = lane & 7;

    const f32x4 z4 = {0.f, 0.f, 0.f, 0.f};
    f32x4 acc[4][4];
#pragma unroll
    for (int i = 0; i < 4; i++)
#pragma unroll
        for (int j = 0; j < 4; j++) acc[i][j] = z4;

    for (int kt = 0; kt < DN; kt += BK) {
        __syncthreads();
#pragma unroll
        for (int it = 0; it < 4; ++it) {
            const int r = wave * 32 + it * 8 + sr8;
            const int cg = cl ^ (r & 7);
            async16(Zb + (size_t)(m0 + r) * DN + kt + cg * 8,
                    As + (wave * 32 + it * 8) * BK);
            async16(Wob + (size_t)(n0 + r) * DN + kt + cg * 8,
                    Bs + (wave * 32 + it * 8) * BK);
        }
        __syncthreads();
#pragma unroll
        for (int ks = 0; ks < BK; ks += 32) {
            bf16x8 af[4], bfr[4];
#pragma unroll
            for (int i = 0; i < 4; i++) {
                const int r = wm + i * 16 + l16;
                const int ch = ((ks >> 3) + quad) ^ (r & 7);
                af[i] = *(const bf16x8*)(As + r * BK + ch * 8);
            }
#pragma unroll
            for (int j = 0; j < 4; j++) {
                const int r = wn + j * 16 + l16;
                const int ch = ((ks >> 3) + quad) ^ (r & 7);
                bfr[j] = *(const bf16x8*)(Bs + r * BK + ch * 8);
            }
#pragma unroll
            for (int i = 0; i < 4; i++)
#pragma unroll
                for (int j = 0; j < 4; j++)
                    acc[i][j] = __builtin_amdgcn_mfma_f32_16x16x32_bf16(af[i], bfr[j], acc[i][j], 0, 0, 0);
        }
    }

#pragma unroll
    for (int i = 0; i < 4; i++)
#pragma unroll
        for (int j = 0; j < 4; j++) {
            int n = n0 + wn + j * 16 + l16;
#pragma unroll
            for (int r = 0; r < 4; r++) {
                int m = m0 + wm + i * 16 + quad * 4 + r;
                Out[(size_t)m * DM + n] = acc[i][j][r];
            }
        }
}

// ---------------- single-pass hierarchical scan for one time chunk ----------------
// Block = (batch b, 32-neuron slice), 1024 threads = 32 tg x 32 neurons. Phase 1 computes
// AND REGISTER-HOLDS per-step d, u, y=mp*(1-sw)*gelu(raw), msw=mp*sw (64 VGPRs, unrolled);
// phase 2 is pure register math + Z stores -> activations read ONCE (42 vs 67 MB/chunk).
__global__ __launch_bounds__(1024) void scan_fused(
    const u16* __restrict__ omd_a, const u16* __restrict__ sig_a,
    const u16* __restrict__ raw_a, const u16* __restrict__ modp_a,
    float* __restrict__ state_cur, const float* __restrict__ sw_logit,
    u16* __restrict__ Z, float* __restrict__ fs_out, int ci_t)
{
    __shared__ float Ds[32][32];
    __shared__ float Ss[32][32];
    __shared__ float Is[32][32];

    const int tid = threadIdx.x;
    const int nl = tid & 31;
    const int tg = tid >> 5;
    const int bx = blockIdx.x;               // BB * (DN/32) = 256 blocks
    const int nsl = bx & 127;
    const int b = bx >> 7;
    const int n = nsl * 32 + nl;

    const size_t base = ((size_t)(b * TC + tg * SCH)) * DN + n;   // chunk-local rows

    const float sw = 1.f / (1.f + __expf(-sw_logit[n]));
    const float osw = 1.f - sw;

    float dv[SCH], uv[SCH], yv[SCH], mswv[SCH];

    // phase 1: sub-chunk summary, hold recurrence inputs in registers
    float D = 1.f, s = 0.f;
#pragma unroll
    for (int t = 0; t < SCH; t++) {
        size_t idx = base + (size_t)t * DN;
        float omd = bf2f(omd_a[idx]);
        float sg = bf2f(sig_a[idx]);
        float rw = bf2f(raw_a[idx]);
        float mp = bf2f(modp_a[idx]);
        float d = 1.f - omd;
        float u = omd * sg * tanh_fast(rw);
        float g2 = 0.5f * rw * (1.f + erf_fast(rw * 0.70710678f));  // exact gelu
        dv[t] = d; uv[t] = u;
        yv[t] = mp * osw * g2;
        mswv[t] = mp * sw;
        D *= d;
        s = d * s + u;
    }
    Ds[tg][nl] = D;
    Ss[tg][nl] = s;
    __syncthreads();

    // prefix combine: tg==0 threads (one per neuron) walk the 32 summaries
    if (tg == 0) {
        float si = state_cur[b * DN + n];
        Is[0][nl] = si;
        for (int c = 0; c < 31; c++) {
            si = Ds[c][nl] * si + Ss[c][nl];
            Is[c + 1][nl] = si;
        }
    }
    __syncthreads();

    // phase 2: register-only re-scan, emit Z
    float s2 = Is[tg][nl];
    const size_t gbase = ((size_t)(b * TT + ci_t * TC + tg * SCH)) * DN + n;
#pragma unroll
    for (int t = 0; t < SCH; t++) {
        s2 = dv[t] * s2 + uv[t];
        Z[gbase + (size_t)t * DN] = f2bf(yv[t] + mswv[t] * s2);
    }
    if (tg == 31) {
        state_cur[b * DN + n] = s2;                 // carry to next chunk
        if (ci_t == NTC - 1) fs_out[b * DN + n] = s2;  // final_state output
    }
}

// ---------------- host launcher ----------------
extern "C" void kernel_launch(void* const* d_in, const int* in_sizes, int n_in,
                              void* d_out, int out_size, void* d_ws, size_t ws_size,
                              hipStream_t stream)
{
    const float* x = (const float*)d_in[0];
    const float* state = (const float*)d_in[1];
    const float* W_main = (const float*)d_in[2];
    const float* W_gate = (const float*)d_in[3];
    const float* W_mod = (const float*)d_in[4];
    const float* W_out = (const float*)d_in[5];
    const float* W_delta = (const float*)d_in[6];
    const float* b_delta = (const float*)d_in[7];
    const float* A_log = (const float*)d_in[8];
    const float* sw_logit = (const float*)d_in[9];

    float* out = (float*)d_out;                       // [B,T,Dm] fp32
    float* fs_out = out + (size_t)MR * DM;            // final_state [B,Dn]

    const size_t NM = (size_t)MR * DN;
    u16* Zb = (u16*)d_ws;                             // 67.11 MB
    u16* raw_c = Zb + NM;                             // 4 x 8.39 MB
    u16* sig_c = raw_c + CN;
    u16* modp_c = sig_c + CN;
    u16* omd_c = modp_c + CN;
    u16* W4b = omd_c + CN;                            // 33.55 MB
    u16* xb = W4b + (size_t)4 * DN * DM;              // 16.78 MB
    u16* woutb = xb + (size_t)MR * DM;                // 8.39 MB
    float* state_cur = (float*)(woutb + (size_t)DM * DN); // 32 KB
    // total = 159,416,320 B  (< 160,202,752 proven available)

    // one fused conversion launch: x + 4 proj weights + W_out + state copy
    {
        const int total4 = (MR * DM) / 4 + 5 * ((DN * DM) / 4) + (BB * DN) / 4;
        cvt7_kernel<<<(total4 + 255) / 256, 256, 0, stream>>>(
            (const float4*)x, (const float4*)W_main, (const float4*)W_gate,
            (const float4*)W_mod, (const float4*)W_delta, (const float4*)W_out,
            (const float4*)state,
            (ushort4*)xb, (ushort4*)W4b, (ushort4*)woutb, (float4*)state_cur);
    }

    for (int ci = 0; ci < NTC; ci++) {
        gemm4_kernel<<<1024, 256, 0, stream>>>(xb, W4b, raw_c, sig_c, modp_c, omd_c,
                                               A_log, b_delta, ci);
        scan_fused<<<BB * (DN / 32), 1024, 0, stream>>>(omd_c, sig_c, raw_c, modp_c,
                                                        state_cur, sw_logit,
                                                        Zb, fs_out, ci);
    }

    // split output GEMM: two half-M launches so gemm4's counters surface in top-5
    gemm_out_kernel<<<256, 256, 0, stream>>>(Zb, woutb, out, 0);
    gemm_out_kernel<<<256, 256, 0, stream>>>(Zb, woutb, out, 32);
}

// Round 5
// 744.246 us; speedup vs baseline: 1.0324x; 1.0112x over previous
//
#include <hip/hip_runtime.h>
#include <hip/hip_bf16.h>
#include <stdint.h>

#define DM 1024            // d_model
#define DN 4096            // d_neuron
#define BB 2               // batch
#define TT 4096            // seq
#define MR (BB*TT)         // 8192 total GEMM rows
#define TC 512             // time chunk
#define NTC (TT/TC)        // 8 time chunks
#define CR (BB*TC)         // 1024 rows per chunk
#define CN ((size_t)CR*DN) // per-chunk activation elems (4,194,304)
#define SCH 16             // scan sub-chunk (32 tg x 16 = TC)

typedef unsigned short u16;
typedef __attribute__((ext_vector_type(8))) short bf16x8;
typedef __attribute__((ext_vector_type(4))) float f32x4;

__device__ __forceinline__ float bf2f(u16 u) {
    unsigned int x = ((unsigned int)u) << 16; float f; __builtin_memcpy(&f, &x, 4); return f;
}
__device__ __forceinline__ u16 f2bf(float f) {
    __hip_bfloat16 h = __float2bfloat16(f); u16 u; __builtin_memcpy(&u, &h, 2); return u;
}
// fast tanh: 1 - 2/(exp(2x)+1); exact at +-inf, abs err ~1e-7
__device__ __forceinline__ float tanh_fast(float x) {
    float e = __expf(2.f * x);
    return 1.f - 2.f / (e + 1.f);
}
// A&S 7.1.26 erf poly, max abs err 1.5e-7
__device__ __forceinline__ float erf_fast(float x) {
    float ax = fabsf(x);
    float t = 1.f / (1.f + 0.3275911f * ax);
    float y = t * (0.254829592f + t * (-0.284496736f + t * (1.421413741f +
              t * (-1.453152027f + t * 1.061405429f))));
    float r = 1.f - y * __expf(-ax * ax);
    return copysignf(r, x);
}
// async global->LDS, 16 B per lane (dest = wave-uniform base + lane*16)
__device__ __forceinline__ void async16(const void* g, void* l) {
    __builtin_amdgcn_global_load_lds(
        (const __attribute__((address_space(1))) void*)(uintptr_t)g,
        (__attribute__((address_space(3))) void*)(uint32_t)(uintptr_t)l,
        16, 0, 0);
}

// -------- fused conversion: x + 4 proj weights + W_out (fp32->bf16) + state copy --------
__global__ void cvt7_kernel(const float4* __restrict__ x,
                            const float4* __restrict__ w0, const float4* __restrict__ w1,
                            const float4* __restrict__ w2, const float4* __restrict__ w3,
                            const float4* __restrict__ wo, const float4* __restrict__ st,
                            ushort4* __restrict__ xb, ushort4* __restrict__ w4b,
                            ushort4* __restrict__ woutb, float4* __restrict__ state_cur)
{
    const int XQ = (MR * DM) / 4;        // 2,097,152
    const int WQ = (DN * DM) / 4;        // 1,048,576 = 2^20
    const int SQ = XQ + 5 * WQ;          // start of state segment
    int i = blockIdx.x * 256 + threadIdx.x;
    if (i >= SQ) {                        // state passthrough (BB*DN/4 = 2048 float4)
        int j = i - SQ;
        if (j < (BB * DN) / 4) state_cur[j] = st[j];
        return;
    }
    const float4* s; ushort4* d;
    if (i < XQ) { s = x + i; d = xb + i; }
    else {
        int j = i - XQ;
        int seg = j >> 20;
        int off = j & (WQ - 1);
        if (seg < 4) {
            const float4* ws = (seg == 0) ? w0 : (seg == 1) ? w1 : (seg == 2) ? w2 : w3;
            s = ws + off; d = w4b + j;
        } else {
            s = wo + off; d = woutb + off;
        }
    }
    float4 v = *s;
    ushort4 o; o.x = f2bf(v.x); o.y = f2bf(v.y); o.z = f2bf(v.z); o.w = f2bf(v.w);
    *d = o;
}

#define BM 128
#define BN 128
#define BK 64

// ---------------- 4 input projections for one time chunk, fused activations ----------------
// ROUND-12: BIT-IDENTICAL to round-0 (measurement target -- counters must map to this
// exact kernel). Round-4 finding: per-block K-chain is the floor of the 2-barrier
// structure (~1.1us/step); gemm4's 4 co-resident blocks overlap POORLY (4.1us effective
// per step-gen) while gemm_out's 2 blocks overlap near-perfectly. Cause unknown ->
// this round surfaces gemm4's counters via gemm_out K-split (see below).
__global__ __launch_bounds__(256, 4) void gemm4_kernel(
    const u16* __restrict__ Xb,             // bf16 [8192][1024]
    const u16* __restrict__ W4b,            // bf16 [4][4096][1024]
    u16* __restrict__ raw_o, u16* __restrict__ sig_o,
    u16* __restrict__ modp_o, u16* __restrict__ omd_o,
    const float* __restrict__ A_log, const float* __restrict__ b_delta, int ci)
{
    const int bid = blockIdx.x;              // 0..1023
    const int xcd = bid & 7;
    const int g = bid >> 3;                  // 0..127
    const int m_idx = g & 7;
    const int pair = xcd * 16 + (g >> 3);    // 0..127 = 32 n-tiles x 4 w
    const int n_idx = pair & 31;
    const int w = pair >> 5;

    const u16* Wp = W4b + (size_t)w * DN * DM;
    u16* Op = (w == 0) ? raw_o : (w == 1) ? sig_o : (w == 2) ? modp_o : omd_o;
    const int n0 = n_idx * BN;
    const int m0 = m_idx * BM;

    alignas(16) __shared__ u16 As[BM * BK];
    alignas(16) __shared__ u16 Bs[BN * BK];

    const int tid = threadIdx.x;
    const int lane = tid & 63;
    const int wave = tid >> 6;
    const int wm = (wave >> 1) * 64;
    const int wn = (wave & 1) * 64;
    const int l16 = lane & 15;
    const int quad = lane >> 4;
    const int sr8 = lane >> 3;
    const int cl = lane & 7;

    const f32x4 z4 = {0.f, 0.f, 0.f, 0.f};
    f32x4 acc[4][4];
#pragma unroll
    for (int i = 0; i < 4; i++)
#pragma unroll
        for (int j = 0; j < 4; j++) acc[i][j] = z4;

    for (int kt = 0; kt < DM; kt += BK) {
        __syncthreads();
#pragma unroll
        for (int it = 0; it < 4; ++it) {
            const int r = wave * 32 + it * 8 + sr8;
            const int cg = cl ^ (r & 7);                  // XOR-8 swizzle
            async16(Wp + (size_t)(n0 + r) * DM + kt + cg * 8,
                    Bs + (wave * 32 + it * 8) * BK);
            const int lr = m0 + r;
            const int xrow = ((lr >> 9) << 12) + ci * TC + (lr & (TC - 1));
            async16(Xb + (size_t)xrow * DM + kt + cg * 8,
                    As + (wave * 32 + it * 8) * BK);
        }
        __syncthreads();
#pragma unroll
        for (int ks = 0; ks < BK; ks += 32) {
            bf16x8 af[4], bfr[4];
#pragma unroll
            for (int i = 0; i < 4; i++) {
                const int r = wm + i * 16 + l16;
                const int ch = ((ks >> 3) + quad) ^ (r & 7);
                af[i] = *(const bf16x8*)(As + r * BK + ch * 8);
            }
#pragma unroll
            for (int j = 0; j < 4; j++) {
                const int r = wn + j * 16 + l16;
                const int ch = ((ks >> 3) + quad) ^ (r & 7);
                bfr[j] = *(const bf16x8*)(Bs + r * BK + ch * 8);
            }
#pragma unroll
            for (int i = 0; i < 4; i++)
#pragma unroll
                for (int j = 0; j < 4; j++)
                    acc[i][j] = __builtin_amdgcn_mfma_f32_16x16x32_bf16(af[i], bfr[j], acc[i][j], 0, 0, 0);
        }
    }

    // hoisted per-column params for w=3 (n depends only on j)
    float Aj[4], bdj[4];
    if (w == 3) {
#pragma unroll
        for (int j = 0; j < 4; j++) {
            int n = n0 + wn + j * 16 + l16;
            Aj[j] = __expf(A_log[n]);
            bdj[j] = b_delta[n];
        }
    }

    // epilogue: C/D layout col=lane&15, row=quad*4+reg (m89-verified)
#pragma unroll
    for (int i = 0; i < 4; i++) {
#pragma unroll
        for (int j = 0; j < 4; j++) {
            int n = n0 + wn + j * 16 + l16;
#pragma unroll
            for (int r = 0; r < 4; r++) {
                int m = m0 + wm + i * 16 + quad * 4 + r;
                float z = acc[i][j][r];
                float o;
                if (w == 0) {
                    o = z;                                    // raw
                } else if (w == 1) {
                    o = 1.f / (1.f + __expf(-z));             // sigmoid gate
                } else if (w == 2) {
                    o = 1.f + tanh_fast(z);                   // 1 + mod
                } else {
                    float v = z + bdj[j];                     // softplus, stable
                    float sp = fmaxf(v, 0.f) + __logf(1.f + __expf(-fabsf(v)));
                    o = 1.f - __expf(-Aj[j] * sp);            // 1 - decay
                }
                Op[(size_t)m * DN + n] = f2bf(o);
            }
        }
    }
}

// ---------------- output GEMM: out[m][dm] = sum_k Z[m][k]*W_out[dm][k], K=4096 ----------------
// ROUND-12: K-SPLIT into two launches (k0 = 0 and DN/2; second accumulates into Out).
// Purpose: each launch has a 32-step chain (~40us) < gemm4 (~66us), so ALL top-5
// profiler slots finally show gemm4. Cost bounded: +67MB mostly-L3 RMW traffic
// (~+5-10us vs the 77us single launch). Body otherwise VERBATIM round-6; the K-chain
// is the floor (round-4: half-M at 1 blk/CU = 70.7us vs full at 2 blk/CU = 77us).
__global__ __launch_bounds__(256, 4) void gemm_out_kernel(
    const u16* __restrict__ Zb, const u16* __restrict__ Wob, float* __restrict__ Out,
    int k0, int accum)
{
    const int bid = blockIdx.x;              // 0..511
    const int xcd = bid & 7;
    const int g = bid >> 3;                  // 0..63
    const int n_idx = g & 7;
    const int m_idx = xcd * 8 + (g >> 3);    // 0..63
    const int n0 = n_idx * BN;
    const int m0 = m_idx * BM;

    alignas(16) __shared__ u16 As[BM * BK];
    alignas(16) __shared__ u16 Bs[BN * BK];

    const int tid = threadIdx.x;
    const int lane = tid & 63;
    const int wave = tid >> 6;
    const int wm = (wave >> 1) * 64;
    const int wn = (wave & 1) * 64;
    const int l16 = lane & 15;
    const int quad = lane >> 4;
    const int sr8 = lane >> 3;
    const int cl = lane & 7;

    const f32x4 z4 = {0.f, 0.f, 0.f, 0.f};
    f32x4 acc[4][4];
#pragma unroll
    for (int i = 0; i < 4; i++)
#pragma unroll
        for (int j = 0; j < 4; j++) acc[i][j] = z4;

    for (int kt = k0; kt < k0 + DN / 2; kt += BK) {
        __syncthreads();
#pragma unroll
        for (int it = 0; it < 4; ++it) {
            const int r = wave * 32 + it * 8 + sr8;
            const int cg = cl ^ (r & 7);
            async16(Zb + (size_t)(m0 + r) * DN + kt + cg * 8,
                    As + (wave * 32 + it * 8) * BK);
            async16(Wob + (size_t)(n0 + r) * DN + kt + cg * 8,
                    Bs + (wave * 32 + it * 8) * BK);
        }
        __syncthreads();
#pragma unroll
        for (int ks = 0; ks < BK; ks += 32) {
            bf16x8 af[4], bfr[4];
#pragma unroll
            for (int i = 0; i < 4; i++) {
                const int r = wm + i * 16 + l16;
                const int ch = ((ks >> 3) + quad) ^ (r & 7);
                af[i] = *(const bf16x8*)(As + r * BK + ch * 8);
            }
#pragma unroll
            for (int j = 0; j < 4; j++) {
                const int r = wn + j * 16 + l16;
                const int ch = ((ks >> 3) + quad) ^ (r & 7);
                bfr[j] = *(const bf16x8*)(Bs + r * BK + ch * 8);
            }
#pragma unroll
            for (int i = 0; i < 4; i++)
#pragma unroll
                for (int j = 0; j < 4; j++)
                    acc[i][j] = __builtin_amdgcn_mfma_f32_16x16x32_bf16(af[i], bfr[j], acc[i][j], 0, 0, 0);
        }
    }

#pragma unroll
    for (int i = 0; i < 4; i++)
#pragma unroll
        for (int j = 0; j < 4; j++) {
            int n = n0 + wn + j * 16 + l16;
#pragma unroll
            for (int r = 0; r < 4; r++) {
                int m = m0 + wm + i * 16 + quad * 4 + r;
                size_t idx = (size_t)m * DM + n;
                if (accum) Out[idx] += acc[i][j][r];
                else       Out[idx]  = acc[i][j][r];
            }
        }
}

// ---------------- single-pass hierarchical scan for one time chunk ----------------
// Block = (batch b, 32-neuron slice), 1024 threads = 32 tg x 32 neurons. Phase 1 computes
// AND REGISTER-HOLDS per-step d, u, y=mp*(1-sw)*gelu(raw), msw=mp*sw (64 VGPRs, unrolled);
// phase 2 is pure register math + Z stores -> activations read ONCE (42 vs 67 MB/chunk).
__global__ __launch_bounds__(1024) void scan_fused(
    const u16* __restrict__ omd_a, const u16* __restrict__ sig_a,
    const u16* __restrict__ raw_a, const u16* __restrict__ modp_a,
    float* __restrict__ state_cur, const float* __restrict__ sw_logit,
    u16* __restrict__ Z, float* __restrict__ fs_out, int ci_t)
{
    __shared__ float Ds[32][32];
    __shared__ float Ss[32][32];
    __shared__ float Is[32][32];

    const int tid = threadIdx.x;
    const int nl = tid & 31;
    const int tg = tid >> 5;
    const int bx = blockIdx.x;               // BB * (DN/32) = 256 blocks
    const int nsl = bx & 127;
    const int b = bx >> 7;
    const int n = nsl * 32 + nl;

    const size_t base = ((size_t)(b * TC + tg * SCH)) * DN + n;   // chunk-local rows

    const float sw = 1.f / (1.f + __expf(-sw_logit[n]));
    const float osw = 1.f - sw;

    float dv[SCH], uv[SCH], yv[SCH], mswv[SCH];

    // phase 1: sub-chunk summary, hold recurrence inputs in registers
    float D = 1.f, s = 0.f;
#pragma unroll
    for (int t = 0; t < SCH; t++) {
        size_t idx = base + (size_t)t * DN;
        float omd = bf2f(omd_a[idx]);
        float sg = bf2f(sig_a[idx]);
        float rw = bf2f(raw_a[idx]);
        float mp = bf2f(modp_a[idx]);
        float d = 1.f - omd;
        float u = omd * sg * tanh_fast(rw);
        float g2 = 0.5f * rw * (1.f + erf_fast(rw * 0.70710678f));  // exact gelu
        dv[t] = d; uv[t] = u;
        yv[t] = mp * osw * g2;
        mswv[t] = mp * sw;
        D *= d;
        s = d * s + u;
    }
    Ds[tg][nl] = D;
    Ss[tg][nl] = s;
    __syncthreads();

    // prefix combine: tg==0 threads (one per neuron) walk the 32 summaries
    if (tg == 0) {
        float si = state_cur[b * DN + n];
        Is[0][nl] = si;
        for (int c = 0; c < 31; c++) {
            si = Ds[c][nl] * si + Ss[c][nl];
            Is[c + 1][nl] = si;
        }
    }
    __syncthreads();

    // phase 2: register-only re-scan, emit Z
    float s2 = Is[tg][nl];
    const size_t gbase = ((size_t)(b * TT + ci_t * TC + tg * SCH)) * DN + n;
#pragma unroll
    for (int t = 0; t < SCH; t++) {
        s2 = dv[t] * s2 + uv[t];
        Z[gbase + (size_t)t * DN] = f2bf(yv[t] + mswv[t] * s2);
    }
    if (tg == 31) {
        state_cur[b * DN + n] = s2;                 // carry to next chunk
        if (ci_t == NTC - 1) fs_out[b * DN + n] = s2;  // final_state output
    }
}

// ---------------- host launcher ----------------
extern "C" void kernel_launch(void* const* d_in, const int* in_sizes, int n_in,
                              void* d_out, int out_size, void* d_ws, size_t ws_size,
                              hipStream_t stream)
{
    const float* x = (const float*)d_in[0];
    const float* state = (const float*)d_in[1];
    const float* W_main = (const float*)d_in[2];
    const float* W_gate = (const float*)d_in[3];
    const float* W_mod = (const float*)d_in[4];
    const float* W_out = (const float*)d_in[5];
    const float* W_delta = (const float*)d_in[6];
    const float* b_delta = (const float*)d_in[7];
    const float* A_log = (const float*)d_in[8];
    const float* sw_logit = (const float*)d_in[9];

    float* out = (float*)d_out;                       // [B,T,Dm] fp32
    float* fs_out = out + (size_t)MR * DM;            // final_state [B,Dn]

    const size_t NM = (size_t)MR * DN;
    u16* Zb = (u16*)d_ws;                             // 67.11 MB
    u16* raw_c = Zb + NM;                             // 4 x 8.39 MB
    u16* sig_c = raw_c + CN;
    u16* modp_c = sig_c + CN;
    u16* omd_c = modp_c + CN;
    u16* W4b = omd_c + CN;                            // 33.55 MB
    u16* xb = W4b + (size_t)4 * DN * DM;              // 16.78 MB
    u16* woutb = xb + (size_t)MR * DM;                // 8.39 MB
    float* state_cur = (float*)(woutb + (size_t)DM * DN); // 32 KB
    // total = 159,416,320 B  (< 160,202,752 proven available)

    // one fused conversion launch: x + 4 proj weights + W_out + state copy
    {
        const int total4 = (MR * DM) / 4 + 5 * ((DN * DM) / 4) + (BB * DN) / 4;
        cvt7_kernel<<<(total4 + 255) / 256, 256, 0, stream>>>(
            (const float4*)x, (const float4*)W_main, (const float4*)W_gate,
            (const float4*)W_mod, (const float4*)W_delta, (const float4*)W_out,
            (const float4*)state,
            (ushort4*)xb, (ushort4*)W4b, (ushort4*)woutb, (float4*)state_cur);
    }

    for (int ci = 0; ci < NTC; ci++) {
        gemm4_kernel<<<1024, 256, 0, stream>>>(xb, W4b, raw_c, sig_c, modp_c, omd_c,
                                               A_log, b_delta, ci);
        scan_fused<<<BB * (DN / 32), 1024, 0, stream>>>(omd_c, sig_c, raw_c, modp_c,
                                                        state_cur, sw_logit,
                                                        Zb, fs_out, ci);
    }

    // K-split output GEMM (two ~40us dispatches so gemm4 fills the top-5 window)
    gemm_out_kernel<<<512, 256, 0, stream>>>(Zb, woutb, out, 0, 0);
    gemm_out_kernel<<<512, 256, 0, stream>>>(Zb, woutb, out, DN / 2, 1);
}